// Round 7
// baseline (17190.887 us; speedup 1.0000x reference)
//
#include <hip/hip_runtime.h>
#include <math.h>

#define TSTEPS 256
#define CDIM 171
#define XSTR 6400          // 256 (padded x) + 6*1024 (h1,h1',h2,h2',h3,h3')
#define SEQB (TSTEPS*CDIM)

// FLAGS region layout (u32 indices)
#define GB_OFF    0        // [256] flat global-barrier flags (one per WG)
#define DECF_OFF  256      // [88] decoder-done flags (g<88)
#define XCNT_OFF  512      // [8] per-XCD WG counts
#define GREG_OFF  520      // [1] global registration count
#define ARR2_OFF  1024     // [8][256] per-XCD local-barrier flags
#define NFLAGS    4096

typedef short v8s __attribute__((ext_vector_type(8)));
typedef float v4f __attribute__((ext_vector_type(4)));

static __device__ __forceinline__ unsigned short f2bf(float f) {
  unsigned int u = __float_as_uint(f);
  u += 0x7fffu + ((u >> 16) & 1u);          // RTNE
  return (unsigned short)(u >> 16);
}
static __device__ __forceinline__ float bf2f(unsigned short h) {
  return __uint_as_float(((unsigned int)h) << 16);
}
static __device__ __forceinline__ float sigf(float x) { return 1.0f / (1.0f + expf(-x)); }

// dtype probe (verified earlier): bf16 pairs put a bf16 exponent in bits[14:7]
// of each u32; genuine fp32 puts uniform mantissa bits there.
static __device__ __forceinline__ bool probe_bf16(const unsigned int* w) {
  int c = 0;
  #pragma unroll
  for (int i = 0; i < 8; ++i) {
    unsigned e = (w[i] >> 7) & 0xFFu;
    c += (e >= 90u && e <= 145u) ? 1 : 0;
  }
  return c == 8;
}
static __device__ __forceinline__ float getv(const void* p, bool bf, size_t i) {
  return bf ? bf2f(((const unsigned short*)p)[i]) : ((const float*)p)[i];
}

static __device__ __forceinline__ unsigned ld_agent(const unsigned* p) {
  return __hip_atomic_load(p, __ATOMIC_RELAXED, __HIP_MEMORY_SCOPE_AGENT);
}
static __device__ __forceinline__ void st_agent(unsigned* p, unsigned v) {
  __hip_atomic_store(p, v, __ATOMIC_RELAXED, __HIP_MEMORY_SCOPE_AGENT);
}
static __device__ __forceinline__ void st_agent_us(unsigned short* p, unsigned short v) {
  __hip_atomic_store(p, v, __ATOMIC_RELAXED, __HIP_MEMORY_SCOPE_AGENT);
}
// 16B agent (sc1) load, NO embedded wait — caller manages vmcnt batching.
static __device__ __forceinline__ v8s lda16(const unsigned short* p) {
  v8s v;
  asm volatile("global_load_dwordx4 %0, %1, off sc1" : "=v"(v) : "v"(p));
  return v;
}

// ---------------------------------------------------------------------------
// init: seed X + 8 XCD replicas, bias sums, zero flags, repack weights:
//   WL1 [4096][1280] = [wih1 padded to 256 | whh1]
//   WL2/WL3 [4096][2048] = [wih | whh]
//   WDEC [176][1024] = dec_w zero-padded rows
//   XR   [8][128][XSTR] per-XCD activation replicas
//   XGT  [256][128][256] = bf16 ground-truth x (optional, ws-permitting)
// ---------------------------------------------------------------------------
__global__ __launch_bounds__(256) void init_kernel(
    const void* seq, const void* wih1, const void* whh1,
    const void* bih1, const void* bhh1,
    const void* wih2, const void* whh2, const void* bih2, const void* bhh2,
    const void* wih3, const void* whh3, const void* bih3, const void* bhh3,
    const void* decw,
    unsigned short* __restrict__ X, float* __restrict__ BS,
    unsigned* __restrict__ flags,
    unsigned short* __restrict__ WL1, unsigned short* __restrict__ WL2,
    unsigned short* __restrict__ WL3, unsigned short* __restrict__ WDEC,
    unsigned short* __restrict__ XR, unsigned short* __restrict__ XGT,
    const int* __restrict__ gtp, const int* __restrict__ condp)
{
  const int tid = blockIdx.x * 256 + threadIdx.x;
  const int NT = 2048 * 256;
  const bool bfm = probe_bf16((const unsigned int*)seq);
  int gt = gtp[0];
  const bool p0 = 0 < gt;

  for (int i = tid; i < 128 * XSTR; i += NT) {
    int b = i / XSTR, c = i - b * XSTR;
    unsigned short v = 0;
    if (c < CDIM && p0) v = f2bf(getv(seq, bfm, (size_t)b * SEQB + c));
    X[i] = v;
  }
  for (int i = tid; i < 8 * 128 * XSTR; i += NT) {   // replicas = X image
    int r = i % (128 * XSTR);
    int b = r / XSTR, c = r - b * XSTR;
    unsigned short v = 0;
    if (c < CDIM && p0) v = f2bf(getv(seq, bfm, (size_t)b * SEQB + c));
    XR[i] = v;
  }
  const void* bis[3] = {bih1, bih2, bih3};
  const void* bhs[3] = {bhh1, bhh2, bhh3};
  for (int i = tid; i < 3 * 4096; i += NT) {
    int l = i >> 12, n = i & 4095;
    BS[i] = getv(bis[l], bfm, n) + getv(bhs[l], bfm, n);
  }
  for (int i = tid; i < NFLAGS; i += NT) flags[i] = 0u;
  for (int i = tid; i < 4096 * 1280; i += NT) {
    int r = i / 1280, c = i - r * 1280;
    float v;
    if (c < CDIM)      v = getv(wih1, bfm, (size_t)r * CDIM + c);
    else if (c < 256)  v = 0.f;
    else               v = getv(whh1, bfm, (size_t)r * 1024 + (c - 256));
    WL1[i] = f2bf(v);
  }
  for (int i = tid; i < 4096 * 2048; i += NT) {
    int r = i >> 11, c = i & 2047;
    size_t o = (size_t)r * 1024 + (c & 1023);
    WL2[i] = f2bf((c < 1024) ? getv(wih2, bfm, o) : getv(whh2, bfm, o));
    WL3[i] = f2bf((c < 1024) ? getv(wih3, bfm, o) : getv(whh3, bfm, o));
  }
  for (int i = tid; i < 176 * 1024; i += NT) {
    int r = i >> 10, c = i & 1023;
    WDEC[i] = (r < CDIM) ? f2bf(getv(decw, bfm, (size_t)r * 1024 + c)) : (unsigned short)0;
  }
  if (XGT) {
    for (int i = tid; i < TSTEPS * 128 * 256; i += NT) {
      int t = i >> 15, b = (i >> 8) & 127, c = i & 255;
      unsigned short v = 0;
      if (c < CDIM) v = f2bf(getv(seq, bfm, (size_t)b * SEQB + (size_t)t * CDIM + c));
      XGT[i] = v;
    }
  }
}

// ---------------------------------------------------------------------------
// FLAT fence-free global barrier: arrive-store + one gang-poll round.
// Release = agent h-stores drained by the entry __syncthreads' implicit
// vmcnt(0); no wbl2/inv anywhere. Replaces the hierarchical leader chain
// (5 MALL hops) with 2. Proven components: flat poll (R1), fence-free
// release (R4/R5). WATCHDOG: budget converts deadlock into a fast
// wrong-answer finish with counters.
// ---------------------------------------------------------------------------
static __device__ __forceinline__ void gbar_flat(
    unsigned* fl, int g, unsigned tgt, int wave, int lane, unsigned& budget)
{
  __syncthreads();                    // vmcnt(0): my agent stores are in MALL
  if (threadIdx.x == 0) st_agent(fl + GB_OFF + g, tgt);
  if (wave == 0) {
    const unsigned* b = fl + GB_OFF;
    for (;;) {
      unsigned a0 = ld_agent(b + lane),       a1 = ld_agent(b + 64 + lane);
      unsigned a2 = ld_agent(b + 128 + lane), a3 = ld_agent(b + 192 + lane);
      if (__all((int)((a0 >= tgt) & (a1 >= tgt) & (a2 >= tgt) & (a3 >= tgt))))
        break;
      if (budget == 0) break;
      --budget; __builtin_amdgcn_s_sleep(1);
    }
  }
  __syncthreads();
}

// Replica copy: this XCD's WGs pull the just-written 256KB h-bank from MALL
// (agent dword loads, 8 in flight per thread) into the XCD-private replica
// (plain write-back stores -> local L2).
static __device__ __forceinline__ void xcopy(
    unsigned short* __restrict__ dst, const unsigned short* __restrict__ src,
    int hoff, unsigned rank, unsigned NX, int tid)
{
  if (NX == 32u) {                      // 8192 threads, 65536 dwords: 8/thread
    const unsigned d0 = rank * 256u + (unsigned)tid;
    unsigned vv[8];
    #pragma unroll
    for (int k = 0; k < 8; ++k) {
      unsigned d = d0 + 8192u * k;
      size_t off = (size_t)(d >> 9) * XSTR + hoff + ((size_t)(d & 511u) << 1);
      vv[k] = ld_agent((const unsigned*)(src + off));
    }
    #pragma unroll
    for (int k = 0; k < 8; ++k) {
      unsigned d = d0 + 8192u * k;
      size_t off = (size_t)(d >> 9) * XSTR + hoff + ((size_t)(d & 511u) << 1);
      *(unsigned*)(dst + off) = vv[k];
    }
  } else {
    for (unsigned d = rank * 256u + (unsigned)tid; d < 65536u; d += NX * 256u) {
      size_t off = (size_t)(d >> 9) * XSTR + hoff + ((size_t)(d & 511u) << 1);
      *(unsigned*)(dst + off) = ld_agent((const unsigned*)(src + off));
    }
  }
}

// Intra-XCD copy-done barrier. L1-only buffer_inv moved BEFORE the poll
// (off the critical path): after inv, later plain loads refill L1 from the
// XCD L2, which holds the fresh replica once the poll succeeds.
static __device__ __forceinline__ void xbar(
    unsigned* fl, unsigned xcd, unsigned rank, unsigned NX,
    unsigned G, int wave, int lane, unsigned& budget)
{
  __syncthreads();                    // vmcnt(0): my replica stores are in L2
  if (threadIdx.x == 0) st_agent(fl + ARR2_OFF + xcd * 256 + rank, G);
  if (wave == 0) {
    asm volatile("buffer_inv" ::: "memory");       // L1-only invalidate
    const unsigned* ab = fl + ARR2_OFF + xcd * 256;
    for (;;) {
      unsigned ok = 1u;
      #pragma unroll
      for (int k = 0; k < 4; ++k) {
        unsigned r = (unsigned)lane + 64u * k;
        if (r < NX) ok &= (ld_agent(ab + r) >= G) ? 1u : 0u;
      }
      if (__all((int)ok)) break;
      if (budget == 0) break;
      --budget; __builtin_amdgcn_s_sleep(1);
    }
  }
  __syncthreads();
}

// MFMA phase: wave's K-slice against register-resident B frags, 8 M-tiles.
// A cols map through [a0 | a1] split at bnd (activation double-banking).
// A-reads are PLAIN loads from the XCD-local replica (L2-warm).
template<int NCH>
static __device__ __forceinline__ void mfma_phase(
    const v8s* wf, const unsigned short* __restrict__ Xb,
    int a0, int bnd, int a1, int kbase, v4f* acc)
{
  #pragma unroll
  for (int i = 0; i < 8; ++i) acc[i] = (v4f){0.f, 0.f, 0.f, 0.f};
  #pragma unroll
  for (int c = 0; c < NCH; ++c) {
    const int acol = kbase + 32 * c;
    const int xcol = (acol < bnd) ? (a0 + acol) : (a1 + acol - bnd);
    const unsigned short* ap = Xb + xcol;
    #pragma unroll
    for (int m = 0; m < 8; ++m) {
      v8s a = *(const v8s*)(ap + (size_t)(16 * m) * XSTR);
      acc[m] = __builtin_amdgcn_mfma_f32_16x16x32_bf16(a, wf[c], acc[m], 0, 0, 0);
    }
  }
}

// LDS 4-way K-reduce + register-local gate math + agent bf16 h store to MALL.
// lred: col-major XOR swizzle — stores and reads both 2 lanes/bank (free).
static __device__ __forceinline__ void lstm_epilogue(
    v4f* acc, float* lred, int wave, int lane,
    const float* bs4, float* cst2,
    unsigned short* __restrict__ X, int hoff, int g)
{
  const int l15 = lane & 15, quad = lane >> 4;
  float* myp = lred + wave * 2048;
  #pragma unroll
  for (int m = 0; m < 8; ++m)
    #pragma unroll
    for (int j = 0; j < 4; ++j)
      myp[m * 256 + l15 * 16 + ((4 * quad + j) ^ ((l15 >> 1) & 3))] = acc[m][j];
  __syncthreads();
  const int ri = lane >> 2, hc = lane & 3;
  #pragma unroll
  for (int e = 0; e < 2; ++e) {
    const int m = 2 * wave + e;
    float z[4];
    #pragma unroll
    for (int k = 0; k < 4; ++k) z[k] = bs4[k];
    #pragma unroll
    for (int w2 = 0; w2 < 4; ++w2) {
      const float* pp = lred + w2 * 2048 + m * 256;
      #pragma unroll
      for (int k = 0; k < 4; ++k) {
        const int col = hc + 4 * k;
        z[k] += pp[col * 16 + (ri ^ ((col >> 1) & 3))];
      }
    }
    float cn = sigf(z[1]) * cst2[e] + sigf(z[0]) * tanhf(z[2]);
    float h  = sigf(z[3]) * tanhf(cn);
    cst2[e] = cn;
    const int row = 32 * wave + 16 * e + ri;
    st_agent_us(X + (size_t)row * XSTR + hoff + 4 * g + hc, f2bf(h));
  }
}

// ---------------------------------------------------------------------------
// Persistent kernel. Per step: 3 flat gbar + 3 xcopy + 3 xbar. Decoder of
// step t-1 is a SOLO-WAVE0 tile (K=1024 in one wave, no LDS) merged into
// step t's L1 window: it overlaps waves 1-3's L1 MFMA. dec->L1 x hand-off
// is an 88-producer flag mini-sync polled only by wave0; x is read straight
// from MALL with pipelined sc1 loads (1KB/wave). No 4th sync slot.
// ---------------------------------------------------------------------------
__global__ __launch_bounds__(256, 1) void persist(
    const unsigned short* __restrict__ WL1, const unsigned short* __restrict__ WL2,
    const unsigned short* __restrict__ WL3, const unsigned short* __restrict__ WDEC,
    const float* __restrict__ BS, unsigned short* __restrict__ X,
    unsigned* __restrict__ flags, unsigned short* __restrict__ XR,
    const void* __restrict__ seq, const void* __restrict__ decb,
    void* __restrict__ outp, const unsigned short* __restrict__ XGT,
    const int* __restrict__ gtp, const int* __restrict__ condp)
{
  const int g = blockIdx.x;
  const int tid = threadIdx.x, wave = tid >> 6, lane = tid & 63;
  const int l15 = lane & 15, quad = lane >> 4;
  const bool bf = probe_bf16((const unsigned int*)seq);
  int gt = gtp[0]; int per = gt + condp[0]; if (per < 1) per = 1;
  unsigned budget = 20000000u;   // watchdog: total poll iters per wave

  // ---- XCD registration (for xcopy/xbar) + one-time rendezvous ----
  __shared__ unsigned s_rank;
  unsigned xcd;
  asm volatile("s_getreg_b32 %0, hwreg(HW_REG_XCC_ID)" : "=s"(xcd));
  xcd &= 7u;
  if (tid == 0) {
    s_rank = __hip_atomic_fetch_add(flags + XCNT_OFF + xcd, 1u,
                                    __ATOMIC_RELAXED, __HIP_MEMORY_SCOPE_AGENT);
    __hip_atomic_fetch_add(flags + GREG_OFF, 1u,
                           __ATOMIC_RELEASE, __HIP_MEMORY_SCOPE_AGENT);
  }
  __syncthreads();
  const unsigned rank = s_rank;
  if (wave == 0 && lane == 0) {
    while (__hip_atomic_load(flags + GREG_OFF, __ATOMIC_ACQUIRE,
                             __HIP_MEMORY_SCOPE_AGENT) < 256u) {
      if (budget == 0) break;
      --budget; __builtin_amdgcn_s_sleep(4);
    }
  }
  __syncthreads();
  const unsigned NX = ld_agent(flags + XCNT_OFF + xcd);

  unsigned short* XRb = XR + (size_t)xcd * (128 * XSTR);   // my XCD's replica

  // ---- weight fragments (VGPR-resident) ----
  const int br = 1024 * (l15 >> 2) + 4 * g + (l15 & 3);
  v8s w1f[10], w2f[16], w3f[16];
  {
    const unsigned short* p = WL1 + (size_t)br * 1280 + 320 * wave + 8 * quad;
    #pragma unroll
    for (int c = 0; c < 10; ++c) w1f[c] = *(const v8s*)(p + 32 * c);
  }
  {
    const unsigned short* p = WL2 + (size_t)br * 2048 + 512 * wave + 8 * quad;
    #pragma unroll
    for (int c = 0; c < 16; ++c) w2f[c] = *(const v8s*)(p + 32 * c);
  }
  {
    const unsigned short* p = WL3 + (size_t)br * 2048 + 512 * wave + 8 * quad;
    #pragma unroll
    for (int c = 0; c < 16; ++c) w3f[c] = *(const v8s*)(p + 32 * c);
  }
  const int dm = g / 11, dn = g - dm * 11;
  float bsr[3][4];
  #pragma unroll
  for (int l = 0; l < 3; ++l)
    #pragma unroll
    for (int gm = 0; gm < 4; ++gm)
      bsr[l][gm] = BS[4096 * l + 1024 * gm + 4 * g + (lane & 3)];
  float dbv = 0.f;
  if (g < 88) { int col = 16 * dn + l15; if (col < CDIM) dbv = getv(decb, bf, col); }

  float cst1[2] = {0.f, 0.f}, cst2v[2] = {0.f, 0.f}, cst3[2] = {0.f, 0.f};
  __shared__ float lred[8192];                       // [4 waves][8 tiles][16][16]
  const unsigned short* Xb = XRb + (size_t)l15 * XSTR + 8 * quad;  // lane A-base
  unsigned bgen = 0, dg = 0;
  v4f acc[8];

  for (int t = 0; t < TSTEPS; ++t) {
    const int p_ = t & 1, q_ = p_ ^ 1;
    const bool pt = (t % per) < gt;                  // ground-truth step?
    if (t > 0 && !pt) ++dg;                          // dec handoff gen (uniform)

    // ---- merged dec(t-1): solo wave0, g<88 (overlaps waves1-3 L1) ----
    if (t > 0 && wave == 0 && g < 88) {
      const unsigned short* ap = XRb + (size_t)(16 * dm + l15) * XSTR
                               + (4352 + 1024 * q_) + 8 * quad;   // h3(t-1)
      const unsigned short* wp = WDEC + (size_t)(16 * dn + l15) * 1024 + 8 * quad;
      v4f da = (v4f){0.f, 0.f, 0.f, 0.f};
      #pragma unroll
      for (int c = 0; c < 32; ++c) {
        v8s a = *(const v8s*)(ap + 32 * c);
        v8s w = *(const v8s*)(wp + 32 * c);
        da = __builtin_amdgcn_mfma_f32_16x16x32_bf16(a, w, da, 0, 0, 0);
      }
      const int col = 16 * dn + l15;
      #pragma unroll
      for (int j = 0; j < 4; ++j) {
        float v = da[j] + dbv;
        const int brow = 16 * dm + 4 * quad + j;
        if (col < CDIM) {
          const size_t oidx = (size_t)brow * SEQB + (size_t)(t - 1) * CDIM + col;
          if (bf) ((unsigned short*)outp)[oidx] = f2bf(v);
          else    ((float*)outp)[oidx] = v;
          if (!pt) st_agent_us(X + (size_t)brow * XSTR + col, f2bf(v));
        }
      }
      if (!pt) {
        asm volatile("s_waitcnt vmcnt(0)" ::: "memory");   // drain x stores
        if (lane == 0) st_agent(flags + DECF_OFF + g, dg);
      }
    }

    // ---- L1 ----
    if (wave == 0) {
      #pragma unroll
      for (int i = 0; i < 8; ++i) acc[i] = (v4f){0.f, 0.f, 0.f, 0.f};
      if (pt) {
        if (XGT) {
          const unsigned short* xb = XGT + ((size_t)t * 128 + l15) * 256 + 8 * quad;
          #pragma unroll
          for (int c = 0; c < 8; ++c)
            #pragma unroll
            for (int m = 0; m < 8; ++m) {
              v8s a = *(const v8s*)(xb + 32 * c + (size_t)(16 * m) * 256);
              acc[m] = __builtin_amdgcn_mfma_f32_16x16x32_bf16(a, w1f[c], acc[m], 0, 0, 0);
            }
        } else {
          #pragma unroll
          for (int c = 0; c < 8; ++c) {
            const int col0 = 32 * c + 8 * quad;
            #pragma unroll
            for (int m = 0; m < 8; ++m) {
              const size_t so = (size_t)(l15 + 16 * m) * SEQB + (size_t)t * CDIM;
              v8s a;
              #pragma unroll
              for (int j = 0; j < 8; ++j) {
                const int cc = col0 + j;
                unsigned short hv = 0;
                if (cc < CDIM)
                  hv = bf ? ((const unsigned short*)seq)[so + cc]
                          : f2bf(((const float*)seq)[so + cc]);
                a[j] = (short)hv;
              }
              acc[m] = __builtin_amdgcn_mfma_f32_16x16x32_bf16(a, w1f[c], acc[m], 0, 0, 0);
            }
          }
        }
      } else {
        // self-fed: wait for 88 dec producers, then pipelined sc1 x-loads
        if (t > 0) {
          const unsigned* df = flags + DECF_OFF;
          for (;;) {
            unsigned a = ld_agent(df + lane);
            unsigned b2 = (lane < 24) ? ld_agent(df + 64 + lane) : dg;
            if (__all((int)((a >= dg) & (b2 >= dg)))) break;
            if (budget == 0) break;
            --budget; __builtin_amdgcn_s_sleep(1);
          }
        }
        v8s bA[8], bB[8];
        #define XISSUE(BUF, MM) do { \
            const unsigned short* bp_ = X + (size_t)(l15 + 16 * (MM)) * XSTR + 8 * quad; \
            _Pragma("unroll") \
            for (int c_ = 0; c_ < 8; ++c_) BUF[c_] = lda16(bp_ + 32 * c_); \
          } while (0)
        XISSUE(bA, 0);
        #pragma unroll
        for (int mm = 0; mm < 8; mm += 2) {
          XISSUE(bB, mm + 1);
          asm volatile("s_waitcnt vmcnt(8)" ::: "memory");
          __builtin_amdgcn_sched_barrier(0);
          #pragma unroll
          for (int c = 0; c < 8; ++c)
            acc[mm] = __builtin_amdgcn_mfma_f32_16x16x32_bf16(bA[c], w1f[c], acc[mm], 0, 0, 0);
          if (mm + 2 < 8) {
            XISSUE(bA, mm + 2);
            asm volatile("s_waitcnt vmcnt(8)" ::: "memory");
          } else {
            asm volatile("s_waitcnt vmcnt(0)" ::: "memory");
          }
          __builtin_amdgcn_sched_barrier(0);
          #pragma unroll
          for (int c = 0; c < 8; ++c)
            acc[mm + 1] = __builtin_amdgcn_mfma_f32_16x16x32_bf16(bB[c], w1f[c], acc[mm + 1], 0, 0, 0);
        }
        #undef XISSUE
      }
      // chains 8,9: h1(t-1) from replica (plain loads)
      #pragma unroll
      for (int c = 8; c < 10; ++c) {
        const unsigned short* ap = Xb + (256 + 1024 * q_) + (32 * c - 256);
        #pragma unroll
        for (int m = 0; m < 8; ++m) {
          v8s a = *(const v8s*)(ap + (size_t)(16 * m) * XSTR);
          acc[m] = __builtin_amdgcn_mfma_f32_16x16x32_bf16(a, w1f[c], acc[m], 0, 0, 0);
        }
      }
    } else {
      mfma_phase<10>(w1f, Xb, 0, 256, 256 + 1024 * q_, 320 * wave, acc);
    }
    lstm_epilogue(acc, lred, wave, lane, bsr[0], cst1, X, 256 + 1024 * p_, g);

    gbar_flat(flags, g, ++bgen, wave, lane, budget);
    xcopy(XRb, X, 256 + 1024 * p_, rank, NX, tid);
    xbar(flags, xcd, rank, NX, bgen, wave, lane, budget);
    mfma_phase<16>(w2f, Xb, 256 + 1024 * p_, 1024, 2304 + 1024 * q_, 512 * wave, acc);
    lstm_epilogue(acc, lred, wave, lane, bsr[1], cst2v, X, 2304 + 1024 * p_, g);

    gbar_flat(flags, g, ++bgen, wave, lane, budget);
    xcopy(XRb, X, 2304 + 1024 * p_, rank, NX, tid);
    xbar(flags, xcd, rank, NX, bgen, wave, lane, budget);
    mfma_phase<16>(w3f, Xb, 2304 + 1024 * p_, 1024, 4352 + 1024 * q_, 512 * wave, acc);
    lstm_epilogue(acc, lred, wave, lane, bsr[2], cst3, X, 4352 + 1024 * p_, g);

    gbar_flat(flags, g, ++bgen, wave, lane, budget);
    xcopy(XRb, X, 4352 + 1024 * p_, rank, NX, tid);
    xbar(flags, xcd, rank, NX, bgen, wave, lane, budget);
  }

  // ---- final dec(255): output only ----
  if (wave == 0 && g < 88) {
    const unsigned short* ap = XRb + (size_t)(16 * dm + l15) * XSTR
                             + (4352 + 1024 * 1) + 8 * quad;   // p_(255)=1
    const unsigned short* wp = WDEC + (size_t)(16 * dn + l15) * 1024 + 8 * quad;
    v4f da = (v4f){0.f, 0.f, 0.f, 0.f};
    #pragma unroll
    for (int c = 0; c < 32; ++c) {
      v8s a = *(const v8s*)(ap + 32 * c);
      v8s w = *(const v8s*)(wp + 32 * c);
      da = __builtin_amdgcn_mfma_f32_16x16x32_bf16(a, w, da, 0, 0, 0);
    }
    const int col = 16 * dn + l15;
    #pragma unroll
    for (int j = 0; j < 4; ++j) {
      float v = da[j] + dbv;
      const int brow = 16 * dm + 4 * quad + j;
      if (col < CDIM) {
        const size_t oidx = (size_t)brow * SEQB + (size_t)255 * CDIM + col;
        if (bf) ((unsigned short*)outp)[oidx] = f2bf(v);
        else    ((float*)outp)[oidx] = v;
      }
    }
  }
}

// ---------------------------------------------------------------------------
// Workspace (bytes; XGT used only if ws_size permits, required total 59.3MB):
//   X     @ 0         : [128][6400] bf16          (1,638,400)
//   BS    @ 1638400   : [3][4096] fp32            (49,152)
//   FLAGS @ 1687552   : [4096] u32                (16,384)
//   XR    @ 1720320   : [8][128][6400] bf16       (13,107,200)
//   WL1   @ 14827520  : [4096][1280] bf16         (10,485,760)
//   WL2   @ 25313280  : [4096][2048] bf16         (16,777,216)
//   WL3   @ 42090496  : [4096][2048] bf16         (16,777,216)
//   WDEC  @ 58867712  : [176][1024] bf16          (360,448)
//   XGT   @ 59228160  : [256][128][256] bf16      (16,777,216, optional)
// ---------------------------------------------------------------------------
extern "C" void kernel_launch(void* const* d_in, const int* in_sizes, int n_in,
                              void* d_out, int out_size, void* d_ws, size_t ws_size,
                              hipStream_t stream) {
  const void* seq  = d_in[0];
  const void* wih1 = d_in[1];  const void* whh1 = d_in[2];
  const void* bih1 = d_in[3];  const void* bhh1 = d_in[4];
  const void* wih2 = d_in[5];  const void* whh2 = d_in[6];
  const void* bih2 = d_in[7];  const void* bhh2 = d_in[8];
  const void* wih3 = d_in[9];  const void* whh3 = d_in[10];
  const void* bih3 = d_in[11]; const void* bhh3 = d_in[12];
  const void* decw = d_in[13]; const void* decb = d_in[14];
  const int* gtp   = (const int*)d_in[15];
  const int* condp = (const int*)d_in[16];

  char* ws = (char*)d_ws;
  unsigned short* X    = (unsigned short*)(ws + 0);
  float*          BS   = (float*)(ws + 1638400);
  unsigned*       FLAGS= (unsigned*)(ws + 1687552);
  unsigned short* XR   = (unsigned short*)(ws + 1720320);
  unsigned short* WL1  = (unsigned short*)(ws + 14827520);
  unsigned short* WL2  = (unsigned short*)(ws + 25313280);
  unsigned short* WL3  = (unsigned short*)(ws + 42090496);
  unsigned short* WDEC = (unsigned short*)(ws + 58867712);
  unsigned short* XGT  = (ws_size >= (size_t)59228160 + (size_t)16777216)
                       ? (unsigned short*)(ws + 59228160) : (unsigned short*)0;

  init_kernel<<<2048, 256, 0, stream>>>(seq, wih1, whh1, bih1, bhh1,
                                        wih2, whh2, bih2, bhh2,
                                        wih3, whh3, bih3, bhh3, decw,
                                        X, BS, FLAGS, WL1, WL2, WL3, WDEC,
                                        XR, XGT, gtp, condp);

  persist<<<256, 256, 0, stream>>>(WL1, WL2, WL3, WDEC, BS, X, FLAGS, XR,
                                   seq, decb, d_out, XGT, gtp, condp);
}